// Round 6
// baseline (417.178 us; speedup 1.0000x reference)
//
#include <hip/hip_runtime.h>

// B=16, C=256, L=2048 -> flat A: N=32768 rows x D=256; K=2048 codewords.
// Outputs (f32, concat): quantized[8388608], indices[32768], loss[1].
// d(n,k) = ||e_k||^2 - 2 x.e ; GEMM via split-bf16 3-pass MFMA; rows with
// top-2 gap < D2 skipped in main, finalized exactly (fp32, x from z_e) by
// rescore. Operands pre-swizzled to the MFMA frag image (16B cell = 8 bf16
// k-octet, [chunk][g][q][lane16]) -> conflict-free b128 LDS + lane-linear DMA.
// B chunks double-buffered in LDS: DMA for t+1 issued before compute of t.

#define ZE_CL   (256 * 2048)
#define NROWS   32768
#define KC      2048
#define DD      256
#define IDX_OFF 8388608
#define LOSS_OFF (8388608 + 32768)
#define D2 8e-3f

typedef __bf16 bf16x4 __attribute__((ext_vector_type(4)));
typedef __bf16 bf16x8 __attribute__((ext_vector_type(8)));
typedef float  f32x4  __attribute__((ext_vector_type(4)));

// ws layout (bytes)
#define EN_OFF  0u
#define EH_OFF  8192u
#define EL_OFF  (EH_OFF + 1048576u)
#define AH_OFF  (EL_OFF + 1048576u)
#define AL_OFF  (AH_OFF + 16777216u)
#define CNT_OFF (AL_OFF + 16777216u)
#define LST_OFF (CNT_OFF + 16u)
#define WS_NEED (LST_OFF + 131072u)

static __device__ inline void gld_lds16(const void* g, void* l) {
    __builtin_amdgcn_global_load_lds(
        (const __attribute__((address_space(1))) void*)g,
        (__attribute__((address_space(3))) void*)l, 16, 0, 0);
}

// ---------------- emb -> enorm + swizzled bf16 hi/lo (64 blocks) ----------------
// Eh/El image: [t=col>>8*8+ch][g=(col>>4)&15][q][c=col&15] 16B cells.
__global__ void vq_prep_emb(const float* __restrict__ emb, float* __restrict__ enorm,
                            __bf16* __restrict__ Eh, __bf16* __restrict__ El) {
    int tid = threadIdx.x;
    int col = blockIdx.x * 32 + (tid >> 3);
    int ch  = tid & 7;
    const float4* src = (const float4*)(emb + (size_t)col * DD) + ch * 8;
    int t8 = col >> 8, g = (col >> 4) & 15, c = col & 15;
    float s = 0.f;
#pragma unroll
    for (int q = 0; q < 4; ++q) {
        float4 v0 = src[q * 2];
        float4 v1 = src[q * 2 + 1];
        float f[8] = {v0.x, v0.y, v0.z, v0.w, v1.x, v1.y, v1.z, v1.w};
        bf16x8 h, l;
#pragma unroll
        for (int j = 0; j < 8; ++j) {
            h[j] = (__bf16)f[j];
            l[j] = (__bf16)(f[j] - (float)h[j]);
            s += f[j] * f[j];
        }
        size_t off = ((size_t)(t8 * 8 + ch) * 16384) + (size_t)(g * 1024 + q * 256 + c * 16);
        *(bf16x8*)((char*)Eh + off) = h;
        *(bf16x8*)((char*)El + off) = l;
    }
    s += __shfl_down(s, 4, 8);
    s += __shfl_down(s, 2, 8);
    s += __shfl_down(s, 1, 8);
    if (ch == 0) enorm[col] = s;
}

// fallback-only enorm
__global__ void vq_enorm(const float* __restrict__ emb, float* __restrict__ enorm) {
    int k = blockIdx.x * blockDim.x + threadIdx.x;
    if (k >= KC) return;
    const float4* e4 = (const float4*)(emb + (size_t)k * DD);
    float s = 0.f;
#pragma unroll
    for (int i = 0; i < DD / 4; ++i) {
        float4 v = e4[i];
        s += v.x * v.x + v.y * v.y + v.z * v.z + v.w * v.w;
    }
    enorm[k] = s;
}

// ---------------- z_e -> swizzled (-2x) hi/lo (+ optional fp32 A for fallback) ----
// Ah/Al image per 64-row block bn: [mi][ch][q][r16] 16B cells (32 KB/plane).
__global__ void vq_transpose_split(const float* __restrict__ ze, float* __restrict__ Aout,
                                   __bf16* __restrict__ Ah, __bf16* __restrict__ Al) {
    __shared__ float T[16 * 272];
    int tid = threadIdx.x;
    int m  = blockIdx.x & 15;
    int lt = blockIdx.x >> 4;
    int l0 = lt * 16;
#pragma unroll
    for (int it = 0; it < 4; ++it) {
        int p   = tid + it * 256;
        int b   = p >> 6;
        int clo = (p >> 2) & 15;
        int l4  = p & 3;
        const float* g = ze + (size_t)b * ZE_CL + (size_t)(m * 16 + clo) * 2048 + l0 + 4 * l4;
        float4 v = *(const float4*)g;
        int jp = 17 * clo + b;
        T[(4 * l4 + 0) * 272 + jp] = v.x;
        T[(4 * l4 + 1) * 272 + jp] = v.y;
        T[(4 * l4 + 2) * 272 + jp] = v.z;
        T[(4 * l4 + 3) * 272 + jp] = v.w;
    }
    __syncthreads();
#pragma unroll
    for (int it = 0; it < 4; ++it) {
        int p  = tid + it * 256;
        int ll = p >> 6;
        int c4 = p & 63;
        int j0 = 4 * c4;
        int base = ll * 272 + 17 * (j0 >> 4) + (j0 & 15);
        float4 v;
        v.x = T[base + 0]; v.y = T[base + 1]; v.z = T[base + 2]; v.w = T[base + 3];
        int n = (l0 + ll) * 16 + m;
        if (Aout) *(float4*)(Aout + (size_t)n * DD + j0) = v;
        if (Ah) {
            float a0 = -2.f * v.x, a1 = -2.f * v.y, a2 = -2.f * v.z, a3 = -2.f * v.w;
            bf16x4 h, l;
            h[0] = (__bf16)a0; l[0] = (__bf16)(a0 - (float)h[0]);
            h[1] = (__bf16)a1; l[1] = (__bf16)(a1 - (float)h[1]);
            h[2] = (__bf16)a2; l[2] = (__bf16)(a2 - (float)h[2]);
            h[3] = (__bf16)a3; l[3] = (__bf16)(a3 - (float)h[3]);
            int bn = n >> 6, mi = (n >> 4) & 3, r = n & 15;
            int ch = j0 >> 5, q = (j0 >> 3) & 3, hb = (j0 & 7) * 2;
            size_t off = (size_t)bn * 32768 + (size_t)((mi * 8 + ch) * 1024 + q * 256 + r * 16 + hb);
            *(bf16x4*)((char*)Ah + off) = h;
            *(bf16x4*)((char*)Al + off) = l;
        }
    }
}

// ---------------- MFMA distance + top-2 argmin + fused epilogue ----------------
// 512 blocks x 4 waves. Block: 64 rows x 2048 cols (64 linear chunks t=nt*8+ch).
// B chunk (16 KB hi + 16 KB lo) double-buffered; DMA for t+1 issued right after
// the barrier protecting buffer t, hidden behind 48 MFMAs.
__global__ __launch_bounds__(256, 2) void vq_main_mfma(
    const __bf16* __restrict__ Ah, const __bf16* __restrict__ Al,
    const __bf16* __restrict__ Eh, const __bf16* __restrict__ El,
    const float* __restrict__ enorm, const float* __restrict__ emb,
    float* out, int* __restrict__ rcount, int* __restrict__ rlist)
{
    __shared__ __align__(16) __bf16 sB[32768];   // 64 KB = 2 buffers x (16K hi + 16K lo)
    __shared__ float sRv[256], sR2[256];
    __shared__ int   sRi[256];
    __shared__ int   sIdx[64], sFlag[64];
    __shared__ float wsum[4];

    const int tid  = threadIdx.x;
    const int wv   = tid >> 6;
    const int lane = tid & 63;
    const int l15  = lane & 15;
    const int quad = lane >> 4;
    const int n0   = blockIdx.x * 64;

    const char* AhB = (const char*)Ah + (size_t)blockIdx.x * 32768;
    const char* AlB = (const char*)Al + (size_t)blockIdx.x * 32768;

    float v1[16], v2[16]; int i1[16];
#pragma unroll
    for (int s = 0; s < 16; ++s) { v1[s] = 3.4e38f; v2[s] = 3.4e38f; i1[s] = 0; }

    // prologue: DMA chunk 0 into buffer 0
    {
        const char* srcH = (const char*)Eh;
        const char* srcL = (const char*)El;
#pragma unroll
        for (int it = 0; it < 4; ++it) {
            int off = (it * 4 + wv) * 1024;
            gld_lds16(srcH + off + lane * 16, (char*)sB + off);
            gld_lds16(srcL + off + lane * 16, (char*)sB + 16384 + off);
        }
    }

    for (int nt = 0; nt < 8; ++nt) {
        f32x4 acc[4][4];
#pragma unroll
        for (int a = 0; a < 4; ++a)
#pragma unroll
            for (int b = 0; b < 4; ++b) acc[a][b] = (f32x4){0.f, 0.f, 0.f, 0.f};

        for (int ch = 0; ch < 8; ++ch) {
            const int t = nt * 8 + ch;
            const int p = t & 1;
            __syncthreads();   // buffer p DMA (issued last iter) done; buffer 1-p free
            if (t < 63) {      // prefetch chunk t+1 into buffer 1-p
                const char* srcH = (const char*)Eh + (size_t)(t + 1) * 16384;
                const char* srcL = (const char*)El + (size_t)(t + 1) * 16384;
                char* dst = (char*)sB + (1 - p) * 32768;
#pragma unroll
                for (int it = 0; it < 4; ++it) {
                    int off = (it * 4 + wv) * 1024;
                    gld_lds16(srcH + off + lane * 16, dst + off);
                    gld_lds16(srcL + off + lane * 16, dst + 16384 + off);
                }
            }
            bf16x8 ah[4], al[4];
#pragma unroll
            for (int mi = 0; mi < 4; ++mi) {
                size_t off = (size_t)((mi * 8 + ch) * 1024 + quad * 256 + l15 * 16);
                ah[mi] = *(const bf16x8*)(AhB + off);
                al[mi] = *(const bf16x8*)(AlB + off);
            }
            const char* buf = (const char*)sB + p * 32768;
            bf16x8 bh[4], bl[4];
#pragma unroll
            for (int nj = 0; nj < 4; ++nj) {
                int boff = (wv * 4 + nj) * 1024 + quad * 256 + l15 * 16;
                bh[nj] = *(const bf16x8*)(buf + boff);
                bl[nj] = *(const bf16x8*)(buf + 16384 + boff);
            }
#pragma unroll
            for (int mi = 0; mi < 4; ++mi)
#pragma unroll
                for (int nj = 0; nj < 4; ++nj)
                    acc[mi][nj] = __builtin_amdgcn_mfma_f32_16x16x32_bf16(ah[mi], bh[nj], acc[mi][nj], 0, 0, 0);
#pragma unroll
            for (int mi = 0; mi < 4; ++mi)
#pragma unroll
                for (int nj = 0; nj < 4; ++nj)
                    acc[mi][nj] = __builtin_amdgcn_mfma_f32_16x16x32_bf16(ah[mi], bl[nj], acc[mi][nj], 0, 0, 0);
#pragma unroll
            for (int mi = 0; mi < 4; ++mi)
#pragma unroll
                for (int nj = 0; nj < 4; ++nj)
                    acc[mi][nj] = __builtin_amdgcn_mfma_f32_16x16x32_bf16(al[mi], bh[nj], acc[mi][nj], 0, 0, 0);
        }
        // fold N-tile into running top-2 (branchless)
#pragma unroll
        for (int nj = 0; nj < 4; ++nj) {
            int k = nt * 256 + wv * 64 + nj * 16 + l15;
            float en = enorm[k];
#pragma unroll
            for (int mi = 0; mi < 4; ++mi)
#pragma unroll
                for (int r = 0; r < 4; ++r) {
                    float d = acc[mi][nj][r] + en;
                    int slot = mi * 4 + r;
                    float nv2 = fminf(v2[slot], fmaxf(v1[slot], d));
                    if (d < v1[slot]) i1[slot] = k;
                    v1[slot] = fminf(v1[slot], d);
                    v2[slot] = nv2;
                }
        }
    }

    // cross-lane top-2 merge over 16 lanes (rows fixed per quad)
#pragma unroll
    for (int slot = 0; slot < 16; ++slot) {
        float a1 = v1[slot], a2 = v2[slot];
        int ai = i1[slot];
#pragma unroll
        for (int m = 1; m < 16; m <<= 1) {
            float b1 = __shfl_xor(a1, m, 64);
            float b2 = __shfl_xor(a2, m, 64);
            int bi = __shfl_xor(ai, m, 64);
            float n2 = fminf(fminf(a2, b2), fmaxf(a1, b1));
            if (b1 < a1) ai = bi;
            a1 = fminf(a1, b1);
            a2 = n2;
        }
        if (l15 == 0) {
            int row = (slot >> 2) * 16 + quad * 4 + (slot & 3);
            sRv[row * 4 + wv] = a1;
            sR2[row * 4 + wv] = a2;
            sRi[row * 4 + wv] = ai;
        }
    }
    __syncthreads();
    if (tid < 64) {
        float a1 = sRv[tid * 4], a2 = sR2[tid * 4];
        int ai = sRi[tid * 4];
#pragma unroll
        for (int w2 = 1; w2 < 4; ++w2) {
            float b1 = sRv[tid * 4 + w2], b2 = sR2[tid * 4 + w2];
            int bi = sRi[tid * 4 + w2];
            float n2 = fminf(fminf(a2, b2), fmaxf(a1, b1));
            if (b1 < a1) ai = bi;
            a1 = fminf(a1, b1);
            a2 = n2;
        }
        int fg = (a2 - a1 < D2) ? 1 : 0;
        sIdx[tid] = ai;
        sFlag[tid] = fg;
        out[IDX_OFF + n0 + tid] = (float)ai;
        if (fg) { int pq = atomicAdd(rcount, 1); rlist[pq] = n0 + tid; }
    }
    __syncthreads();

    // fused epilogue: quantize + loss for non-flagged rows.
    // x' = -0.5*(Ah+Al) (rel err ~1.5e-5 -> loss err ~2e-5, far under threshold).
    float lacc = 0.f;
#pragma unroll
    for (int it = 0; it < 16; ++it) {
        int pp = tid + it * 256;
        int r  = pp >> 6;           // whole wave shares a row -> uniform branch
        int c4 = pp & 63;
        if (!sFlag[r]) {
            int j0 = 4 * c4;
            int mi = r >> 4, r16 = r & 15;
            int ch = j0 >> 5, q4i = (j0 >> 3) & 3, hb = (j0 & 7) * 2;
            size_t aoff = (size_t)((mi * 8 + ch) * 1024 + q4i * 256 + r16 * 16 + hb);
            bf16x4 h = *(const bf16x4*)(AhB + aoff);
            bf16x4 l = *(const bf16x4*)(AlB + aoff);
            int k = sIdx[r];
            float4 q = *(const float4*)(emb + (size_t)k * DD + j0);
            float x0 = -0.5f * ((float)h[0] + (float)l[0]);
            float x1 = -0.5f * ((float)h[1] + (float)l[1]);
            float x2 = -0.5f * ((float)h[2] + (float)l[2]);
            float x3 = -0.5f * ((float)h[3] + (float)l[3]);
            float dx = q.x - x0, dy = q.y - x1, dz = q.z - x2, dw = q.w - x3;
            lacc += dx * dx + dy * dy + dz * dz + dw * dw;
            *(float4*)(out + (size_t)(n0 + r) * DD + j0) = q;
        }
    }
#pragma unroll
    for (int off = 32; off > 0; off >>= 1) lacc += __shfl_down(lacc, off, 64);
    if ((tid & 63) == 0) wsum[tid >> 6] = lacc;
    __syncthreads();
    if (tid == 0) {
        float bs = wsum[0] + wsum[1] + wsum[2] + wsum[3];
        atomicAdd(out + LOSS_OFF, bs * (1.25f / 8388608.0f));
    }
}

// ---------------- exact fp32 finalize of flagged rows (x from z_e) ----------------
__global__ void vq_rescore(const float* __restrict__ ze, const float* __restrict__ emb,
                           const float* __restrict__ enorm, float* out,
                           const int* __restrict__ rcount, const int* __restrict__ rlist) {
    __shared__ float sX[256];
    __shared__ float sV[256];
    __shared__ int   sK[256];
    __shared__ float sP[256];
    int cnt = *rcount;
    int tid = threadIdx.x;
    for (int li = blockIdx.x; li < cnt; li += gridDim.x) {
        int row = rlist[li];
        __syncthreads();
        // exact fp32 x gathered straight from z_e: x[j]=ze[b=j&15][c=(row&15)*16+(j>>4)][l=row>>4]
        sX[tid] = ze[(size_t)(tid & 15) * ZE_CL +
                     (size_t)((row & 15) * 16 + (tid >> 4)) * 2048 + (row >> 4)];
        __syncthreads();
        float bv = 3.4e38f; int bk = 0;
        for (int jj = 0; jj < 8; ++jj) {
            int k = jj * 256 + tid;   // ascending per thread: '<' keeps first
            const float4* e4 = (const float4*)(emb + (size_t)k * DD);
            float dot = 0.f;
#pragma unroll 8
            for (int d4 = 0; d4 < 64; ++d4) {
                float4 e = e4[d4];
                float4 x = *(const float4*)(sX + d4 * 4);
                dot += x.x * e.x + x.y * e.y + x.z * e.z + x.w * e.w;
            }
            float s = enorm[k] - 2.f * dot;
            if (s < bv) { bv = s; bk = k; }
        }
        sV[tid] = bv; sK[tid] = bk;
        __syncthreads();
#pragma unroll
        for (int s = 128; s > 0; s >>= 1) {
            if (tid < s) {
                float vo = sV[tid + s]; int ko = sK[tid + s];
                if (vo < sV[tid] || (vo == sV[tid] && ko < sK[tid])) { sV[tid] = vo; sK[tid] = ko; }
            }
            __syncthreads();
        }
        int k = sK[0];
        float x = sX[tid];
        float q = emb[(size_t)k * DD + tid];
        out[(size_t)row * DD + tid] = q;
        float d = q - x;
        sP[tid] = d * d;
        __syncthreads();
#pragma unroll
        for (int s = 128; s > 0; s >>= 1) {
            if (tid < s) sP[tid] += sP[tid + s];
            __syncthreads();
        }
        if (tid == 0) {
            out[IDX_OFF + row] = (float)k;
            atomicAdd(out + LOSS_OFF, sP[0] * (1.25f / 8388608.0f));
        }
    }
}

// ---------------- fallback fp32 main (only if ws too small) ----------------
__global__ __launch_bounds__(256, 2) void vq_main_f32(const float* __restrict__ emb,
                                                      const float* __restrict__ enorm,
                                                      float* out) {
    const int SA = 68, SE = 68;
    __shared__ float smem[64 * 68 + 64 * 68];
    __shared__ int   sIdx[64];
    __shared__ float wsum[4];
    float* sA = smem;
    float* sEb = smem + 64 * SA;
    float* redv = sEb;
    int*   redi = (int*)(sEb + 64 * 16);
    int tid = threadIdx.x;
    int n0 = blockIdx.x * 64;
    int rg = tid & 15;
    int kg = tid >> 4;
    float minv[4]; int mini[4];
#pragma unroll
    for (int i = 0; i < 4; ++i) { minv[i] = 3.4e38f; mini[i] = 0; }
    const float* A = out;
    for (int kt = 0; kt < KC / 64; ++kt) {
        int k0 = kt * 64;
        float acc[4][4];
#pragma unroll
        for (int i = 0; i < 4; ++i)
#pragma unroll
            for (int j = 0; j < 4; ++j) acc[i][j] = 0.f;
        for (int dc = 0; dc < 4; ++dc) {
            int d0 = dc * 64;
            __syncthreads();
#pragma unroll
            for (int it = 0; it < 4; ++it) {
                int p = tid + it * 256, r = p >> 4, c4 = p & 15;
                *(float4*)(sA + r * SA + 4 * c4) =
                    *(const float4*)(A + (size_t)(n0 + r) * DD + d0 + 4 * c4);
            }
#pragma unroll
            for (int it = 0; it < 4; ++it) {
                int p = tid + it * 256, r = p >> 4, c4 = p & 15;
                *(float4*)(sEb + r * SE + 4 * c4) =
                    *(const float4*)(emb + (size_t)(k0 + r) * DD + d0 + 4 * c4);
            }
            __syncthreads();
#pragma unroll
            for (int d4 = 0; d4 < 16; ++d4) {
                float4 av[4], ev[4];
#pragma unroll
                for (int i = 0; i < 4; ++i) av[i] = *(const float4*)(sA + (rg + 16 * i) * SA + 4 * d4);
#pragma unroll
                for (int j = 0; j < 4; ++j) ev[j] = *(const float4*)(sEb + (kg + 16 * j) * SE + 4 * d4);
#pragma unroll
                for (int i = 0; i < 4; ++i)
#pragma unroll
                    for (int j = 0; j < 4; ++j)
                        acc[i][j] += av[i].x * ev[j].x + av[i].y * ev[j].y +
                                     av[i].z * ev[j].z + av[i].w * ev[j].w;
            }
        }
#pragma unroll
        for (int j = 0; j < 4; ++j) {
            int k = k0 + kg + 16 * j;
            float en = enorm[k];
#pragma unroll
            for (int i = 0; i < 4; ++i) {
                float s = en - 2.f * acc[i][j];
                if (s < minv[i]) { minv[i] = s; mini[i] = k; }
            }
        }
    }
    __syncthreads();
#pragma unroll
    for (int i = 0; i < 4; ++i) {
        int r = rg + 16 * i;
        redv[r * 16 + kg] = minv[i];
        redi[r * 16 + kg] = mini[i];
    }
    __syncthreads();
    if (tid < 64) {
        float bv = redv[tid * 16]; int bi = redi[tid * 16];
        for (int t = 1; t < 16; ++t) {
            float v = redv[tid * 16 + t]; int ii = redi[tid * 16 + t];
            if (v < bv || (v == bv && ii < bi)) { bv = v; bi = ii; }
        }
        sIdx[tid] = bi;
        out[IDX_OFF + n0 + tid] = (float)bi;
    }
    __syncthreads();
    float lacc = 0.f;
#pragma unroll
    for (int it = 0; it < 16; ++it) {
        int p = tid + it * 256, r = p >> 6, c4 = p & 63;
        int k = sIdx[r];
        size_t off = (size_t)(n0 + r) * DD + 4 * c4;
        float4 q = *(const float4*)(emb + (size_t)k * DD + 4 * c4);
        float4 a = *(const float4*)(out + off);
        float dx = q.x - a.x, dy = q.y - a.y, dz = q.z - a.z, dw = q.w - a.w;
        lacc += dx * dx + dy * dy + dz * dz + dw * dw;
        *(float4*)(out + off) = q;
    }
#pragma unroll
    for (int off = 32; off > 0; off >>= 1) lacc += __shfl_down(lacc, off, 64);
    if ((tid & 63) == 0) wsum[tid >> 6] = lacc;
    __syncthreads();
    if (tid == 0) {
        float bs = wsum[0] + wsum[1] + wsum[2] + wsum[3];
        atomicAdd(out + LOSS_OFF, bs * (1.25f / 8388608.0f));
    }
}

extern "C" void kernel_launch(void* const* d_in, const int* in_sizes, int n_in,
                              void* d_out, int out_size, void* d_ws, size_t ws_size,
                              hipStream_t stream) {
    (void)in_sizes; (void)n_in; (void)out_size;
    const float* ze  = (const float*)d_in[0];
    const float* emb = (const float*)d_in[1];
    float* out = (float*)d_out;
    char*  ws  = (char*)d_ws;
    float* enorm = (float*)(ws + EN_OFF);

    hipMemsetAsync((char*)d_out + (size_t)LOSS_OFF * 4, 0, 4, stream);

    if (ws_size >= (size_t)WS_NEED) {
        __bf16* Eh = (__bf16*)(ws + EH_OFF);
        __bf16* El = (__bf16*)(ws + EL_OFF);
        __bf16* Ah = (__bf16*)(ws + AH_OFF);
        __bf16* Al = (__bf16*)(ws + AL_OFF);
        int* rcount = (int*)(ws + CNT_OFF);
        int* rlist  = (int*)(ws + LST_OFF);
        hipMemsetAsync(ws + CNT_OFF, 0, 16, stream);
        vq_prep_emb<<<64, 256, 0, stream>>>(emb, enorm, Eh, El);
        vq_transpose_split<<<2048, 256, 0, stream>>>(ze, (float*)0, Ah, Al);
        vq_main_mfma<<<NROWS / 64, 256, 0, stream>>>(Ah, Al, Eh, El, enorm, emb, out, rcount, rlist);
        vq_rescore<<<64, 256, 0, stream>>>(ze, emb, enorm, out, rcount, rlist);
    } else {
        vq_enorm<<<KC / 256, 256, 0, stream>>>(emb, enorm);
        vq_transpose_split<<<2048, 256, 0, stream>>>(ze, out, (__bf16*)0, (__bf16*)0);
        vq_main_f32<<<NROWS / 64, 256, 0, stream>>>(emb, enorm, out);
    }
}